// Round 3
// baseline (1236.705 us; speedup 1.0000x reference)
//
#include <hip/hip_runtime.h>
#include <hip/hip_bf16.h>

#define N_NODES 10000
#define DIM     256
#define HID     512
#define N_EDGE  320000

typedef __attribute__((ext_vector_type(4))) float  f32x4;
typedef __attribute__((ext_vector_type(8))) __bf16 bf16x8;

// round-to-nearest-even f32 -> bf16 bits
__device__ __forceinline__ unsigned short f2bf(float f) {
    union { float f; unsigned int u; } v; v.f = f;
    unsigned int r = v.u + 0x7FFFu + ((v.u >> 16) & 1u);
    return (unsigned short)(r >> 16);
}

// ---------------------------------------------------------------------------
// SpMM: agg[dst] += x[src] * val   (one wave per edge, lane covers 4 features)
// ---------------------------------------------------------------------------
__global__ void k_spmm(const float* __restrict__ x, const int* __restrict__ esrc,
                       const int* __restrict__ edst, const float* __restrict__ eval,
                       float* __restrict__ agg) {
    int gid  = blockIdx.x * blockDim.x + threadIdx.x;
    int e    = gid >> 6;
    int lane = gid & 63;
    if (e >= N_EDGE) return;
    int   s = esrc[e];
    int   d = edst[e];
    float v = eval[e];
    f32x4 m = *(const f32x4*)(x + (size_t)s * DIM + lane * 4);
    float* ar = agg + (size_t)d * DIM + lane * 4;
    atomicAdd(ar + 0, m.x * v);
    atomicAdd(ar + 1, m.y * v);
    atomicAdd(ar + 2, m.z * v);
    atomicAdd(ar + 3, m.w * v);
}

// ---------------------------------------------------------------------------
// cat = bf16([x | agg])   [N, 512]
// ---------------------------------------------------------------------------
__global__ void k_cat(const float* __restrict__ x, const float* __restrict__ agg,
                      unsigned short* __restrict__ cat) {
    int t  = blockIdx.x * blockDim.x + threadIdx.x;
    int e4 = t * 4;
    if (e4 >= N_NODES * 2 * DIM) return;
    int n = e4 >> 9;
    int c = e4 & 511;
    const float* p = (c < DIM) ? (x + (size_t)n * DIM + c)
                               : (agg + (size_t)n * DIM + (c - DIM));
    f32x4 v = *(const f32x4*)p;
    ushort4 o;
    o.x = f2bf(v.x); o.y = f2bf(v.y); o.z = f2bf(v.z); o.w = f2bf(v.w);
    *(ushort4*)(cat + e4) = o;
}

// ---------------------------------------------------------------------------
// Wt[n][k] = bf16(W[k][n])   (N fixed = 512 for both weight matrices)
// ---------------------------------------------------------------------------
__global__ void k_wt(const float* __restrict__ W, unsigned short* __restrict__ Wt,
                     int K) {
    int t = blockIdx.x * blockDim.x + threadIdx.x;
    if (t >= K * 512) return;
    int k = t >> 9;
    int n = t & 511;
    Wt[(size_t)n * K + k] = f2bf(W[(size_t)k * 512 + n]);
}

// ---------------------------------------------------------------------------
// C = A[M,K] @ Bt[N,K]^T, one 16x16 tile per wave, mfma_f32_16x16x32_bf16.
// MODE 0: relu(acc+bias) -> bf16 out.  MODE 1: prelu(acc+bias) -> f32 out.
// ---------------------------------------------------------------------------
template <int MODE>
__global__ void k_gemm(const unsigned short* __restrict__ A,
                       const unsigned short* __restrict__ Bt,
                       const float* __restrict__ bias,
                       const float* __restrict__ pa,
                       void* __restrict__ outv,
                       int M, int N, int K) {
    int wid  = (blockIdx.x * blockDim.x + threadIdx.x) >> 6;
    int lane = threadIdx.x & 63;
    int tiles_n = N >> 4;
    int tm = wid / tiles_n;
    int tn = wid - tm * tiles_n;
    if (tm * 16 >= M) return;

    int r  = lane & 15;            // A-row / Bt-row (= C-col) within tile
    int k0 = (lane >> 4) * 8;      // fragment K offset

    const bf16x8* ap = (const bf16x8*)(A  + (size_t)(tm * 16 + r) * K + k0);
    const bf16x8* bp = (const bf16x8*)(Bt + (size_t)(tn * 16 + r) * K + k0);

    f32x4 acc = {0.f, 0.f, 0.f, 0.f};
    #pragma unroll
    for (int k = 0; k < HID; k += 32) {   // K == 512 for both GEMMs
        acc = __builtin_amdgcn_mfma_f32_16x16x32_bf16(ap[k >> 3], bp[k >> 3], acc, 0, 0, 0);
    }

    int col  = tn * 16 + (lane & 15);
    int row0 = tm * 16 + (lane >> 4) * 4;
    float b = bias[col];
    if (MODE == 0) {
        unsigned short* out = (unsigned short*)outv;
        #pragma unroll
        for (int i = 0; i < 4; i++) {
            float v = acc[i] + b;
            v = v > 0.f ? v : 0.f;
            out[(size_t)(row0 + i) * N + col] = f2bf(v);
        }
    } else {
        float a = pa[col];
        float* out = (float*)outv;
        #pragma unroll
        for (int i = 0; i < 4; i++) {
            float v = acc[i] + b;
            v = v > 0.f ? v : a * v;
            out[(size_t)(row0 + i) * N + col] = v;
        }
    }
}

// ---------------------------------------------------------------------------
// pred[row] = dot(z[row,:], W2) + b2    (one wave per row)
// ---------------------------------------------------------------------------
__global__ void k_gemv(const float* __restrict__ z, const float* __restrict__ w2,
                       const float* __restrict__ b2, float* __restrict__ pred) {
    int row  = blockIdx.x * 4 + (threadIdx.x >> 6);
    int lane = threadIdx.x & 63;
    if (row >= N_NODES) return;
    const float* zr = z + (size_t)row * HID;
    float acc = 0.f;
    #pragma unroll
    for (int k = lane; k < HID; k += 64) acc += zr[k] * w2[k];
    #pragma unroll
    for (int off = 32; off; off >>= 1) acc += __shfl_down(acc, off);
    if (lane == 0) pred[row] = acc + b2[0];
}

extern "C" void kernel_launch(void* const* d_in, const int* in_sizes, int n_in,
                              void* d_out, int out_size, void* d_ws, size_t ws_size,
                              hipStream_t stream) {
    const float* x    = (const float*)d_in[0];
    const int*   esrc = (const int*)  d_in[1];
    const int*   edst = (const int*)  d_in[2];
    const float* eval = (const float*)d_in[3];
    const float* Wc   = (const float*)d_in[4];
    const float* bc   = (const float*)d_in[5];
    const float* W1   = (const float*)d_in[6];
    const float* b1   = (const float*)d_in[7];
    const float* pa   = (const float*)d_in[8];
    const float* W2   = (const float*)d_in[9];
    const float* b2   = (const float*)d_in[10];
    float* pred = (float*)d_out;

    // workspace layout (all 16B-aligned offsets), total ~52.2 MB
    char* w = (char*)d_ws;
    float*          agg = (float*)w;                               // 10,240,000 B
    unsigned short* cat = (unsigned short*)(w + 10240000);         // 10,240,000 B
    unsigned short* Wct = (unsigned short*)(w + 20480000);         //    524,288 B
    unsigned short* W1t = (unsigned short*)(w + 21004288);         //    524,288 B
    unsigned short* h   = (unsigned short*)(w + 21528576);         // 10,240,000 B
    float*          z   = (float*)(w + 31768576);                  // 20,480,000 B

    hipMemsetAsync(agg, 0, (size_t)N_NODES * DIM * sizeof(float), stream);

    // SpMM: one wave per edge -> E/4 blocks of 256
    k_spmm<<<N_EDGE / 4, 256, 0, stream>>>(x, esrc, edst, eval, agg);

    // cat build: N*512/4 threads
    k_cat<<<(N_NODES * 2 * DIM / 4 + 255) / 256, 256, 0, stream>>>(x, agg, cat);

    // weight transpose+convert
    k_wt<<<(512 * 512) / 256, 256, 0, stream>>>(Wc, Wct, 2 * DIM);
    k_wt<<<(512 * 512) / 256, 256, 0, stream>>>(W1, W1t, HID);

    // GEMMs: (10000/16)*(512/16) = 20000 waves, 4 waves/block
    int nblk = (N_NODES / 16) * (HID / 16) / 4;   // 5000
    k_gemm<0><<<nblk, 256, 0, stream>>>(cat, Wct, bc, nullptr, h, N_NODES, HID, 2 * DIM);
    k_gemm<1><<<nblk, 256, 0, stream>>>(h, W1t, b1, pa, z, N_NODES, HID, HID);

    // final GEMV
    k_gemv<<<(N_NODES + 3) / 4, 256, 0, stream>>>(z, W2, b2, pred);
}

// Round 4
// 280.433 us; speedup vs baseline: 4.4100x; 4.4100x over previous
//
#include <hip/hip_runtime.h>
#include <hip/hip_bf16.h>

#define N_NODES 10000
#define DIM     256
#define HID     512
#define N_EDGE  320000

typedef __attribute__((ext_vector_type(4))) float  f32x4;
typedef __attribute__((ext_vector_type(8))) __bf16 bf16x8;

// round-to-nearest-even f32 -> bf16 bits
__device__ __forceinline__ unsigned short f2bf(float f) {
    union { float f; unsigned int u; } v; v.f = f;
    unsigned int r = v.u + 0x7FFFu + ((v.u >> 16) & 1u);
    return (unsigned short)(r >> 16);
}
// bf16 bits -> f32 (exact)
__device__ __forceinline__ float bf2f(unsigned short u) {
    union { unsigned int i; float f; } v; v.i = ((unsigned int)u) << 16;
    return v.f;
}

// ---------------------------------------------------------------------------
// CSR build step 1: histogram of edge destinations
// ---------------------------------------------------------------------------
__global__ void k_hist(const int* __restrict__ edst, int* __restrict__ deg) {
    int e = blockIdx.x * blockDim.x + threadIdx.x;
    if (e >= N_EDGE) return;
    atomicAdd(&deg[edst[e]], 1);
}

// ---------------------------------------------------------------------------
// CSR build step 2: exclusive prefix scan over deg[0..N) -> offs, pos cursor.
// Single block of 256 threads, 40 elements per thread (256*40 = 10240 >= N).
// ---------------------------------------------------------------------------
__global__ void k_scan(const int* __restrict__ deg, int* __restrict__ offs,
                       int* __restrict__ pos) {
    __shared__ int part[256];
    const int CH = 40;
    int t = threadIdx.x;
    int base = t * CH;
    int s = 0;
    for (int i = 0; i < CH; i++) {
        int idx = base + i;
        if (idx < N_NODES) s += deg[idx];
    }
    part[t] = s;
    __syncthreads();
    // Hillis-Steele inclusive scan over the 256 partials
    for (int off = 1; off < 256; off <<= 1) {
        int u = (t >= off) ? part[t - off] : 0;
        __syncthreads();
        part[t] += u;
        __syncthreads();
    }
    int run = part[t] - s;   // exclusive start of this chunk
    for (int i = 0; i < CH; i++) {
        int idx = base + i;
        if (idx < N_NODES) {
            offs[idx] = run;
            pos[idx]  = run;
            run += deg[idx];
        }
    }
    if (t == 255) offs[N_NODES] = run;   // == N_EDGE
}

// ---------------------------------------------------------------------------
// CSR build step 3: scatter edges into dst-sorted (src, val_bits) pairs
// ---------------------------------------------------------------------------
__global__ void k_scatter(const int* __restrict__ esrc, const int* __restrict__ edst,
                          const float* __restrict__ eval, int* __restrict__ pos,
                          int2* __restrict__ epack) {
    int e = blockIdx.x * blockDim.x + threadIdx.x;
    if (e >= N_EDGE) return;
    int d = edst[e];
    int p = atomicAdd(&pos[d], 1);
    epack[p] = make_int2(esrc[e], __float_as_int(eval[e]));
}

// ---------------------------------------------------------------------------
// cat[n][0..255] = bf16(x[n][0..255])   (first half; agg kernel fills second)
// ---------------------------------------------------------------------------
__global__ void k_cat_x(const float* __restrict__ x, unsigned short* __restrict__ cat) {
    int t = blockIdx.x * blockDim.x + threadIdx.x;
    if (t >= N_NODES * DIM / 4) return;
    int n  = t >> 6;
    int c4 = (t & 63) * 4;
    f32x4 v = *(const f32x4*)(x + (size_t)n * DIM + c4);
    ushort4 o;
    o.x = f2bf(v.x); o.y = f2bf(v.y); o.z = f2bf(v.z); o.w = f2bf(v.w);
    *(ushort4*)(cat + (size_t)n * 2 * DIM + c4) = o;
}

// ---------------------------------------------------------------------------
// Aggregate: one wave per node; lane owns 4 features. Gathers bf16 src rows
// from cat's first half, f32-accumulates, writes bf16 into cat's second half.
// ---------------------------------------------------------------------------
__global__ void k_agg(const int* __restrict__ offs, const int2* __restrict__ epack,
                      unsigned short* __restrict__ cat) {
    int wid  = (blockIdx.x * blockDim.x + threadIdx.x) >> 6;
    int lane = threadIdx.x & 63;
    if (wid >= N_NODES) return;
    int e0 = offs[wid], e1 = offs[wid + 1];
    int c4 = lane * 4;
    f32x4 acc = {0.f, 0.f, 0.f, 0.f};
    for (int e = e0; e < e1; ++e) {
        int2 p = epack[e];                       // wave-uniform
        float v = __int_as_float(p.y);
        ushort4 q = *(const ushort4*)(cat + (size_t)p.x * 2 * DIM + c4);
        acc.x += v * bf2f(q.x);
        acc.y += v * bf2f(q.y);
        acc.z += v * bf2f(q.z);
        acc.w += v * bf2f(q.w);
    }
    ushort4 o;
    o.x = f2bf(acc.x); o.y = f2bf(acc.y); o.z = f2bf(acc.z); o.w = f2bf(acc.w);
    *(ushort4*)(cat + (size_t)wid * 2 * DIM + DIM + c4) = o;
}

// ---------------------------------------------------------------------------
// Wt[n][k] = bf16(W[k][n])   (N fixed = 512 for both weight matrices)
// ---------------------------------------------------------------------------
__global__ void k_wt(const float* __restrict__ W, unsigned short* __restrict__ Wt,
                     int K) {
    int t = blockIdx.x * blockDim.x + threadIdx.x;
    if (t >= K * 512) return;
    int k = t >> 9;
    int n = t & 511;
    Wt[(size_t)n * K + k] = f2bf(W[(size_t)k * 512 + n]);
}

// ---------------------------------------------------------------------------
// C = A[M,K] @ Bt[N,K]^T, one 16x16 tile per wave, mfma_f32_16x16x32_bf16.
// MODE 0: relu(acc+bias) -> bf16 out.  MODE 1: prelu(acc+bias) -> f32 out.
// ---------------------------------------------------------------------------
template <int MODE>
__global__ void k_gemm(const unsigned short* __restrict__ A,
                       const unsigned short* __restrict__ Bt,
                       const float* __restrict__ bias,
                       const float* __restrict__ pa,
                       void* __restrict__ outv,
                       int M, int N, int K) {
    int wid  = (blockIdx.x * blockDim.x + threadIdx.x) >> 6;
    int lane = threadIdx.x & 63;
    int tiles_n = N >> 4;
    int tm = wid / tiles_n;
    int tn = wid - tm * tiles_n;
    if (tm * 16 >= M) return;

    int r  = lane & 15;            // A-row / Bt-row (= C-col) within tile
    int k0 = (lane >> 4) * 8;      // fragment K offset

    const bf16x8* ap = (const bf16x8*)(A  + (size_t)(tm * 16 + r) * K + k0);
    const bf16x8* bp = (const bf16x8*)(Bt + (size_t)(tn * 16 + r) * K + k0);

    f32x4 acc = {0.f, 0.f, 0.f, 0.f};
    #pragma unroll
    for (int k = 0; k < HID; k += 32) {   // K == 512 for both GEMMs
        acc = __builtin_amdgcn_mfma_f32_16x16x32_bf16(ap[k >> 3], bp[k >> 3], acc, 0, 0, 0);
    }

    int col  = tn * 16 + (lane & 15);
    int row0 = tm * 16 + (lane >> 4) * 4;
    float b = bias[col];
    if (MODE == 0) {
        unsigned short* out = (unsigned short*)outv;
        #pragma unroll
        for (int i = 0; i < 4; i++) {
            float v = acc[i] + b;
            v = v > 0.f ? v : 0.f;
            out[(size_t)(row0 + i) * N + col] = f2bf(v);
        }
    } else {
        float a = pa[col];
        float* out = (float*)outv;
        #pragma unroll
        for (int i = 0; i < 4; i++) {
            float v = acc[i] + b;
            v = v > 0.f ? v : a * v;
            out[(size_t)(row0 + i) * N + col] = v;
        }
    }
}

// ---------------------------------------------------------------------------
// pred[row] = dot(z[row,:], W2) + b2    (one wave per row)
// ---------------------------------------------------------------------------
__global__ void k_gemv(const float* __restrict__ z, const float* __restrict__ w2,
                       const float* __restrict__ b2, float* __restrict__ pred) {
    int row  = blockIdx.x * 4 + (threadIdx.x >> 6);
    int lane = threadIdx.x & 63;
    if (row >= N_NODES) return;
    const float* zr = z + (size_t)row * HID;
    float acc = 0.f;
    #pragma unroll
    for (int k = lane; k < HID; k += 64) acc += zr[k] * w2[k];
    #pragma unroll
    for (int off = 32; off; off >>= 1) acc += __shfl_down(acc, off);
    if (lane == 0) pred[row] = acc + b2[0];
}

extern "C" void kernel_launch(void* const* d_in, const int* in_sizes, int n_in,
                              void* d_out, int out_size, void* d_ws, size_t ws_size,
                              hipStream_t stream) {
    const float* x    = (const float*)d_in[0];
    const int*   esrc = (const int*)  d_in[1];
    const int*   edst = (const int*)  d_in[2];
    const float* eval = (const float*)d_in[3];
    const float* Wc   = (const float*)d_in[4];
    const float* bc   = (const float*)d_in[5];
    const float* W1   = (const float*)d_in[6];
    const float* b1   = (const float*)d_in[7];
    const float* pa   = (const float*)d_in[8];
    const float* W2   = (const float*)d_in[9];
    const float* b2   = (const float*)d_in[10];
    float* pred = (float*)d_out;

    // workspace layout (16B-aligned), total ~44.7 MB
    char* w = (char*)d_ws;
    int*            deg   = (int*)w;                               //    40,960 B
    int*            offs  = (int*)(w + 40960);                     //    40,960 B
    int*            pos   = (int*)(w + 81920);                     //    40,960 B
    int2*           epack = (int2*)(w + 122880);                   // 2,560,000 B
    unsigned short* cat   = (unsigned short*)(w + 2682880);        // 10,240,000 B
    unsigned short* Wct   = (unsigned short*)(w + 12922880);       //   524,288 B
    unsigned short* W1t   = (unsigned short*)(w + 13447168);       //   524,288 B
    unsigned short* h     = (unsigned short*)(w + 13971456);       // 10,240,000 B
    float*          z     = (float*)(w + 24211456);                // 20,480,000 B

    // ---- CSR build (replaces 82M-atomic scatter SpMM) ----
    hipMemsetAsync(deg, 0, 10240 * sizeof(int), stream);
    k_hist   <<<(N_EDGE + 255) / 256, 256, 0, stream>>>(edst, deg);
    k_scan   <<<1, 256, 0, stream>>>(deg, offs, pos);
    k_scatter<<<(N_EDGE + 255) / 256, 256, 0, stream>>>(esrc, edst, eval, pos, epack);

    // ---- cat first half (bf16 x), then gather-aggregate into second half ----
    k_cat_x<<<(N_NODES * DIM / 4 + 255) / 256, 256, 0, stream>>>(x, cat);
    k_agg  <<<(N_NODES * 64 + 255) / 256, 256, 0, stream>>>(offs, epack, cat);

    // ---- weight transpose+convert ----
    k_wt<<<(512 * 512) / 256, 256, 0, stream>>>(Wc, Wct, 2 * DIM);
    k_wt<<<(512 * 512) / 256, 256, 0, stream>>>(W1, W1t, HID);

    // ---- GEMMs: (10000/16)*(512/16) = 20000 waves, 4 waves/block ----
    int nblk = (N_NODES / 16) * (HID / 16) / 4;   // 5000
    k_gemm<0><<<nblk, 256, 0, stream>>>(cat, Wct, bc, nullptr, h, N_NODES, HID, 2 * DIM);
    k_gemm<1><<<nblk, 256, 0, stream>>>(h, W1t, b1, pa, z, N_NODES, HID, HID);

    // ---- final GEMV ----
    k_gemv<<<(N_NODES + 3) / 4, 256, 0, stream>>>(z, W2, b2, pred);
}

// Round 5
// 163.843 us; speedup vs baseline: 7.5481x; 1.7116x over previous
//
#include <hip/hip_runtime.h>
#include <hip/hip_bf16.h>

#define N_NODES 10000
#define M_PAD   10112          // 79 * 128
#define DIM     256
#define HID     512
#define KDIM    512            // K for both GEMMs (2*DIM == HID == 512)
#define N_EDGE  320000

typedef __attribute__((ext_vector_type(4))) float  f32x4;
typedef __attribute__((ext_vector_type(8))) __bf16 bf16x8;

// round-to-nearest-even f32 -> bf16 bits
__device__ __forceinline__ unsigned short f2bf(float f) {
    union { float f; unsigned int u; } v; v.f = f;
    unsigned int r = v.u + 0x7FFFu + ((v.u >> 16) & 1u);
    return (unsigned short)(r >> 16);
}
// bf16 bits -> f32 (exact)
__device__ __forceinline__ float bf2f(unsigned short u) {
    union { unsigned int i; float f; } v; v.i = ((unsigned int)u) << 16;
    return v.f;
}

// ---------------------------------------------------------------------------
// CSR build step 1: histogram of edge destinations
// ---------------------------------------------------------------------------
__global__ void k_hist(const int* __restrict__ edst, int* __restrict__ deg) {
    int e = blockIdx.x * blockDim.x + threadIdx.x;
    if (e >= N_EDGE) return;
    atomicAdd(&deg[edst[e]], 1);
}

// ---------------------------------------------------------------------------
// CSR build step 2: exclusive prefix scan (single block, 256 thr x 40 elems)
// ---------------------------------------------------------------------------
__global__ void k_scan(const int* __restrict__ deg, int* __restrict__ offs,
                       int* __restrict__ pos) {
    __shared__ int part[256];
    const int CH = 40;
    int t = threadIdx.x;
    int base = t * CH;
    int s = 0;
    for (int i = 0; i < CH; i++) {
        int idx = base + i;
        if (idx < N_NODES) s += deg[idx];
    }
    part[t] = s;
    __syncthreads();
    for (int off = 1; off < 256; off <<= 1) {
        int u = (t >= off) ? part[t - off] : 0;
        __syncthreads();
        part[t] += u;
        __syncthreads();
    }
    int run = part[t] - s;
    for (int i = 0; i < CH; i++) {
        int idx = base + i;
        if (idx < N_NODES) {
            offs[idx] = run;
            pos[idx]  = run;
            run += deg[idx];
        }
    }
    if (t == 255) offs[N_NODES] = run;
}

// ---------------------------------------------------------------------------
// CSR build step 3: scatter edges into dst-sorted (src, val_bits) pairs
// ---------------------------------------------------------------------------
__global__ void k_scatter(const int* __restrict__ esrc, const int* __restrict__ edst,
                          const float* __restrict__ eval, int* __restrict__ pos,
                          int2* __restrict__ epack) {
    int e = blockIdx.x * blockDim.x + threadIdx.x;
    if (e >= N_EDGE) return;
    int d = edst[e];
    int p = atomicAdd(&pos[d], 1);
    epack[p] = make_int2(esrc[e], __float_as_int(eval[e]));
}

// ---------------------------------------------------------------------------
// cat[n][0..255] = bf16(x[n][0..255])   (first half; agg fills second half)
// ---------------------------------------------------------------------------
__global__ void k_cat_x(const float* __restrict__ x, unsigned short* __restrict__ cat) {
    int t = blockIdx.x * blockDim.x + threadIdx.x;
    if (t >= N_NODES * DIM / 4) return;
    int n  = t >> 6;
    int c4 = (t & 63) * 4;
    f32x4 v = *(const f32x4*)(x + (size_t)n * DIM + c4);
    ushort4 o;
    o.x = f2bf(v.x); o.y = f2bf(v.y); o.z = f2bf(v.z); o.w = f2bf(v.w);
    *(ushort4*)(cat + (size_t)n * 2 * DIM + c4) = o;
}

// ---------------------------------------------------------------------------
// Aggregate: one wave per node, gather bf16 rows, f32 accumulate, bf16 out
// ---------------------------------------------------------------------------
__global__ void k_agg(const int* __restrict__ offs, const int2* __restrict__ epack,
                      unsigned short* __restrict__ cat) {
    int wid  = (blockIdx.x * blockDim.x + threadIdx.x) >> 6;
    int lane = threadIdx.x & 63;
    if (wid >= N_NODES) return;
    int e0 = offs[wid], e1 = offs[wid + 1];
    int c4 = lane * 4;
    f32x4 acc = {0.f, 0.f, 0.f, 0.f};
    for (int e = e0; e < e1; ++e) {
        int2 p = epack[e];
        float v = __int_as_float(p.y);
        ushort4 q = *(const ushort4*)(cat + (size_t)p.x * 2 * DIM + c4);
        acc.x += v * bf2f(q.x);
        acc.y += v * bf2f(q.y);
        acc.z += v * bf2f(q.z);
        acc.w += v * bf2f(q.w);
    }
    ushort4 o;
    o.x = f2bf(acc.x); o.y = f2bf(acc.y); o.z = f2bf(acc.z); o.w = f2bf(acc.w);
    *(ushort4*)(cat + (size_t)wid * 2 * DIM + DIM + c4) = o;
}

// ---------------------------------------------------------------------------
// Wt[n][k] = bf16(W[k][n])   (both weights are 512x512)
// ---------------------------------------------------------------------------
__global__ void k_wt(const float* __restrict__ W, unsigned short* __restrict__ Wt) {
    int t = blockIdx.x * blockDim.x + threadIdx.x;
    if (t >= 512 * 512) return;
    int k = t >> 9;
    int n = t & 511;
    Wt[(size_t)n * 512 + k] = f2bf(W[(size_t)k * 512 + n]);
}

// ---------------------------------------------------------------------------
// LDS-tiled GEMM: C = A[M_PAD,512] @ Bt[512,512]^T, 128x128 tile per block,
// 4 waves (2x2), each wave a 64x64 sub-tile (4x4 frags of 16x16x32 bf16 MFMA).
// LDS rows padded +8 bf16 (stride 144 B) -> conflict-free fragment reads.
// MODE 0: relu(acc+bias) -> bf16 hout.
// MODE 1: prelu(acc+bias) dot w2, column-reduced -> part[8][M_PAD] (fused GEMV).
// ---------------------------------------------------------------------------
#define LDSW 72   // 64 + 8 pad, elements

template <int MODE>
__global__ __launch_bounds__(256)
void k_gemm128(const unsigned short* __restrict__ A,
               const unsigned short* __restrict__ Bt,
               const float* __restrict__ bias,
               const float* __restrict__ pa,
               const float* __restrict__ w2,
               unsigned short* __restrict__ hout,
               float* __restrict__ part) {
    __shared__ unsigned short As[128 * LDSW];
    __shared__ unsigned short Bs[128 * LDSW];

    const int t    = threadIdx.x;
    const int lane = t & 63;
    const int w    = t >> 6;
    const int wr   = w >> 1, wc = w & 1;
    const int tn   = blockIdx.x & 3;          // 4 N-tiles
    const int tm   = blockIdx.x >> 2;         // 79 M-tiles
    const int gm0  = tm * 128, gn0 = tn * 128;

    // staging map: thread t loads 64 B of row (t>>1), col half (t&1)*32
    const int srow = t >> 1;
    const int scol = (t & 1) * 32;
    const unsigned short* gA = A  + (size_t)(gm0 + srow) * KDIM + scol;
    const unsigned short* gB = Bt + (size_t)(gn0 + srow) * KDIM + scol;
    unsigned short* wA = &As[srow * LDSW + scol];
    unsigned short* wB = &Bs[srow * LDSW + scol];

    const int r15 = lane & 15;
    const int kf  = (lane >> 4) * 8;

    f32x4 acc[4][4] = {};

    for (int ks = 0; ks < 8; ++ks) {
        f32x4 va0 = *(const f32x4*)(gA);
        f32x4 va1 = *(const f32x4*)(gA + 8);
        f32x4 va2 = *(const f32x4*)(gA + 16);
        f32x4 va3 = *(const f32x4*)(gA + 24);
        f32x4 vb0 = *(const f32x4*)(gB);
        f32x4 vb1 = *(const f32x4*)(gB + 8);
        f32x4 vb2 = *(const f32x4*)(gB + 16);
        f32x4 vb3 = *(const f32x4*)(gB + 24);
        __syncthreads();                     // prev iter's LDS reads done
        *(f32x4*)(wA)      = va0;
        *(f32x4*)(wA + 8)  = va1;
        *(f32x4*)(wA + 16) = va2;
        *(f32x4*)(wA + 24) = va3;
        *(f32x4*)(wB)      = vb0;
        *(f32x4*)(wB + 8)  = vb1;
        *(f32x4*)(wB + 16) = vb2;
        *(f32x4*)(wB + 24) = vb3;
        __syncthreads();                     // tile visible
        #pragma unroll
        for (int kk = 0; kk < 2; ++kk) {
            bf16x8 af[4], bf[4];
            #pragma unroll
            for (int m = 0; m < 4; ++m)
                af[m] = *(const bf16x8*)&As[(wr * 64 + m * 16 + r15) * LDSW + kk * 32 + kf];
            #pragma unroll
            for (int n = 0; n < 4; ++n)
                bf[n] = *(const bf16x8*)&Bs[(wc * 64 + n * 16 + r15) * LDSW + kk * 32 + kf];
            #pragma unroll
            for (int m = 0; m < 4; ++m)
                #pragma unroll
                for (int n = 0; n < 4; ++n)
                    acc[m][n] = __builtin_amdgcn_mfma_f32_16x16x32_bf16(af[m], bf[n], acc[m][n], 0, 0, 0);
        }
        gA += 64;
        gB += 64;
    }

    const int rq = lane >> 4;                // C row quad
    if (MODE == 0) {
        #pragma unroll
        for (int n = 0; n < 4; ++n) {
            int c = gn0 + wc * 64 + n * 16 + r15;
            float b = bias[c];
            #pragma unroll
            for (int m = 0; m < 4; ++m) {
                #pragma unroll
                for (int i = 0; i < 4; ++i) {
                    int row = gm0 + wr * 64 + m * 16 + rq * 4 + i;
                    float v = acc[m][n][i] + b;
                    v = v > 0.f ? v : 0.f;   // NaN from poison rows -> 0
                    hout[(size_t)row * HID + c] = f2bf(v);
                }
            }
        }
    } else {
        float rsum[4][4] = {};
        #pragma unroll
        for (int n = 0; n < 4; ++n) {
            int c = gn0 + wc * 64 + n * 16 + r15;
            float b = bias[c];
            float a = pa[c];
            float wv = w2[c];
            #pragma unroll
            for (int m = 0; m < 4; ++m)
                #pragma unroll
                for (int i = 0; i < 4; ++i) {
                    float v = acc[m][n][i] + b;
                    v = v > 0.f ? v : a * v;
                    rsum[m][i] += v * wv;
                }
        }
        // reduce over the 16 column-lanes; lane&15==0 holds the sum
        #pragma unroll
        for (int m = 0; m < 4; ++m)
            #pragma unroll
            for (int i = 0; i < 4; ++i) {
                float s = rsum[m][i];
                s += __shfl_xor(s, 1);
                s += __shfl_xor(s, 2);
                s += __shfl_xor(s, 4);
                s += __shfl_xor(s, 8);
                if (r15 == 0) {
                    int row = gm0 + wr * 64 + m * 16 + rq * 4 + i;
                    part[(size_t)(tn * 2 + wc) * M_PAD + row] = s;
                }
            }
    }
}

// ---------------------------------------------------------------------------
// pred[row] = sum_j part[j][row] + b2
// ---------------------------------------------------------------------------
__global__ void k_vout(const float* __restrict__ part, const float* __restrict__ b2,
                       float* __restrict__ pred) {
    int row = blockIdx.x * blockDim.x + threadIdx.x;
    if (row >= N_NODES) return;
    float s = b2[0];
    #pragma unroll
    for (int j = 0; j < 8; ++j) s += part[(size_t)j * M_PAD + row];
    pred[row] = s;
}

extern "C" void kernel_launch(void* const* d_in, const int* in_sizes, int n_in,
                              void* d_out, int out_size, void* d_ws, size_t ws_size,
                              hipStream_t stream) {
    const float* x    = (const float*)d_in[0];
    const int*   esrc = (const int*)  d_in[1];
    const int*   edst = (const int*)  d_in[2];
    const float* eval = (const float*)d_in[3];
    const float* Wc   = (const float*)d_in[4];
    const float* bc   = (const float*)d_in[5];
    const float* W1   = (const float*)d_in[6];
    const float* b1   = (const float*)d_in[7];
    const float* pa   = (const float*)d_in[8];
    const float* W2   = (const float*)d_in[9];
    const float* b2   = (const float*)d_in[10];
    float* pred = (float*)d_out;

    // workspace layout (16B-aligned), total ~24.8 MB
    char* w = (char*)d_ws;
    int*            deg   = (int*)w;                               //     40,960 B
    int*            offs  = (int*)(w + 40960);                     //     40,960 B
    int*            pos   = (int*)(w + 81920);                     //     40,960 B
    int2*           epack = (int2*)(w + 122880);                   //  2,560,000 B
    unsigned short* cat   = (unsigned short*)(w + 2682880);        // 10,354,688 B (M_PAD x 512)
    unsigned short* Wct   = (unsigned short*)(w + 13037568);       //    524,288 B
    unsigned short* W1t   = (unsigned short*)(w + 13561856);       //    524,288 B
    unsigned short* h     = (unsigned short*)(w + 14086144);       // 10,354,688 B (M_PAD x 512)
    float*          partb = (float*)(w + 24440832);                //    323,584 B (8 x M_PAD)

    // ---- CSR build ----
    hipMemsetAsync(deg, 0, 10240 * sizeof(int), stream);
    k_hist   <<<(N_EDGE + 255) / 256, 256, 0, stream>>>(edst, deg);
    k_scan   <<<1, 256, 0, stream>>>(deg, offs, pos);
    k_scatter<<<(N_EDGE + 255) / 256, 256, 0, stream>>>(esrc, edst, eval, pos, epack);

    // ---- cat halves ----
    k_cat_x<<<(N_NODES * DIM / 4 + 255) / 256, 256, 0, stream>>>(x, cat);
    k_agg  <<<(N_NODES * 64 + 255) / 256, 256, 0, stream>>>(offs, epack, cat);

    // ---- weight transpose+convert (both 512x512) ----
    k_wt<<<(512 * 512) / 256, 256, 0, stream>>>(Wc, Wct);
    k_wt<<<(512 * 512) / 256, 256, 0, stream>>>(W1, W1t);

    // ---- tiled GEMMs: 79 M-tiles x 4 N-tiles = 316 blocks ----
    k_gemm128<0><<<316, 256, 0, stream>>>(cat, Wct, bc, nullptr, nullptr, h, nullptr);
    k_gemm128<1><<<316, 256, 0, stream>>>(h, W1t, b1, pa, W2, nullptr, partb);

    // ---- final partial reduce ----
    k_vout<<<(N_NODES + 255) / 256, 256, 0, stream>>>(partb, b2, pred);
}

// Round 6
// 135.117 us; speedup vs baseline: 9.1528x; 1.2126x over previous
//
#include <hip/hip_runtime.h>
#include <hip/hip_bf16.h>

#define N_NODES 10000
#define M_PAD   10112          // 79 * 128
#define DIM     256
#define HID     512
#define KDIM    512            // K for both GEMMs (2*DIM == HID == 512)
#define N_EDGE  320000

typedef __attribute__((ext_vector_type(4))) float  f32x4;
typedef __attribute__((ext_vector_type(8))) __bf16 bf16x8;

// round-to-nearest-even f32 -> bf16 bits
__device__ __forceinline__ unsigned short f2bf(float f) {
    union { float f; unsigned int u; } v; v.f = f;
    unsigned int r = v.u + 0x7FFFu + ((v.u >> 16) & 1u);
    return (unsigned short)(r >> 16);
}
// bf16 bits -> f32 (exact)
__device__ __forceinline__ float bf2f(unsigned short u) {
    union { unsigned int i; float f; } v; v.i = ((unsigned int)u) << 16;
    return v.f;
}

// ---------------------------------------------------------------------------
// Fused prep: blockIdx ranges dispatch 4 independent jobs
//   [0,1250)      : histogram of edge destinations
//   [1250,3750)   : cat[n][0..255] = bf16(x[n][*])
//   [3750,4774)   : Wct = bf16(Wc^T)
//   [4774,5798)   : W1t = bf16(W1^T)
// ---------------------------------------------------------------------------
__global__ void k_prep(const int* __restrict__ edst, int* __restrict__ deg,
                       const float* __restrict__ x, unsigned short* __restrict__ cat,
                       const float* __restrict__ Wc, unsigned short* __restrict__ Wct,
                       const float* __restrict__ W1, unsigned short* __restrict__ W1t) {
    int b = blockIdx.x;
    if (b < 1250) {
        int e = b * 256 + threadIdx.x;
        if (e < N_EDGE) atomicAdd(&deg[edst[e]], 1);
    } else if (b < 3750) {
        int t  = (b - 1250) * 256 + threadIdx.x;   // < 640000 exactly
        int n  = t >> 6;
        int c4 = (t & 63) * 4;
        f32x4 v = *(const f32x4*)(x + (size_t)n * DIM + c4);
        ushort4 o;
        o.x = f2bf(v.x); o.y = f2bf(v.y); o.z = f2bf(v.z); o.w = f2bf(v.w);
        *(ushort4*)(cat + (size_t)n * 2 * DIM + c4) = o;
    } else if (b < 4774) {
        int t = (b - 3750) * 256 + threadIdx.x;
        int k = t >> 9, n = t & 511;
        Wct[(size_t)n * 512 + k] = f2bf(Wc[(size_t)k * 512 + n]);
    } else {
        int t = (b - 4774) * 256 + threadIdx.x;
        int k = t >> 9, n = t & 511;
        W1t[(size_t)n * 512 + k] = f2bf(W1[(size_t)k * 512 + n]);
    }
}

// ---------------------------------------------------------------------------
// CSR build step 2: exclusive prefix scan (single block, 256 thr x 40 elems)
// ---------------------------------------------------------------------------
__global__ void k_scan(const int* __restrict__ deg, int* __restrict__ offs,
                       int* __restrict__ pos) {
    __shared__ int part[256];
    const int CH = 40;
    int t = threadIdx.x;
    int base = t * CH;
    int s = 0;
    for (int i = 0; i < CH; i++) {
        int idx = base + i;
        if (idx < N_NODES) s += deg[idx];
    }
    part[t] = s;
    __syncthreads();
    for (int off = 1; off < 256; off <<= 1) {
        int u = (t >= off) ? part[t - off] : 0;
        __syncthreads();
        part[t] += u;
        __syncthreads();
    }
    int run = part[t] - s;
    for (int i = 0; i < CH; i++) {
        int idx = base + i;
        if (idx < N_NODES) {
            offs[idx] = run;
            pos[idx]  = run;
            run += deg[idx];
        }
    }
    if (t == 255) offs[N_NODES] = run;
}

// ---------------------------------------------------------------------------
// CSR build step 3: scatter edges into dst-sorted (src, val_bits) pairs
// ---------------------------------------------------------------------------
__global__ void k_scatter(const int* __restrict__ esrc, const int* __restrict__ edst,
                          const float* __restrict__ eval, int* __restrict__ pos,
                          int2* __restrict__ epack) {
    int e = blockIdx.x * blockDim.x + threadIdx.x;
    if (e >= N_EDGE) return;
    int d = edst[e];
    int p = atomicAdd(&pos[d], 1);
    epack[p] = make_int2(esrc[e], __float_as_int(eval[e]));
}

// ---------------------------------------------------------------------------
// Aggregate: one wave per node. Lane l preloads edge record e0+l (one vector
// load covers the whole edge block), readlane-broadcasts it, and 4 row
// gathers fly concurrently into 4 independent accumulators.
// ---------------------------------------------------------------------------
__global__ void k_agg(const int* __restrict__ offs, const int2* __restrict__ epack,
                      unsigned short* __restrict__ cat) {
    int wid  = (blockIdx.x * blockDim.x + threadIdx.x) >> 6;
    int lane = threadIdx.x & 63;
    if (wid >= N_NODES) return;
    int e0 = offs[wid], e1 = offs[wid + 1];
    int c4 = lane * 4;
    f32x4 a0 = {0.f,0.f,0.f,0.f}, a1 = a0, a2 = a0, a3 = a0;
    for (int base = e0; base < e1; base += 64) {
        int m = e1 - base;
        if (m > 64) m = 64;
        int2 my = make_int2(0, 0);
        if (lane < m) my = epack[base + lane];
        int j = 0;
        for (; j + 4 <= m; j += 4) {
            int   s0 = __builtin_amdgcn_readlane(my.x, j);
            float v0 = __int_as_float(__builtin_amdgcn_readlane(my.y, j));
            int   s1 = __builtin_amdgcn_readlane(my.x, j + 1);
            float v1 = __int_as_float(__builtin_amdgcn_readlane(my.y, j + 1));
            int   s2 = __builtin_amdgcn_readlane(my.x, j + 2);
            float v2 = __int_as_float(__builtin_amdgcn_readlane(my.y, j + 2));
            int   s3 = __builtin_amdgcn_readlane(my.x, j + 3);
            float v3 = __int_as_float(__builtin_amdgcn_readlane(my.y, j + 3));
            ushort4 q0 = *(const ushort4*)(cat + (size_t)s0 * 2 * DIM + c4);
            ushort4 q1 = *(const ushort4*)(cat + (size_t)s1 * 2 * DIM + c4);
            ushort4 q2 = *(const ushort4*)(cat + (size_t)s2 * 2 * DIM + c4);
            ushort4 q3 = *(const ushort4*)(cat + (size_t)s3 * 2 * DIM + c4);
            a0.x += v0 * bf2f(q0.x); a0.y += v0 * bf2f(q0.y);
            a0.z += v0 * bf2f(q0.z); a0.w += v0 * bf2f(q0.w);
            a1.x += v1 * bf2f(q1.x); a1.y += v1 * bf2f(q1.y);
            a1.z += v1 * bf2f(q1.z); a1.w += v1 * bf2f(q1.w);
            a2.x += v2 * bf2f(q2.x); a2.y += v2 * bf2f(q2.y);
            a2.z += v2 * bf2f(q2.z); a2.w += v2 * bf2f(q2.w);
            a3.x += v3 * bf2f(q3.x); a3.y += v3 * bf2f(q3.y);
            a3.z += v3 * bf2f(q3.z); a3.w += v3 * bf2f(q3.w);
        }
        for (; j < m; ++j) {
            int   s0 = __builtin_amdgcn_readlane(my.x, j);
            float v0 = __int_as_float(__builtin_amdgcn_readlane(my.y, j));
            ushort4 q0 = *(const ushort4*)(cat + (size_t)s0 * 2 * DIM + c4);
            a0.x += v0 * bf2f(q0.x); a0.y += v0 * bf2f(q0.y);
            a0.z += v0 * bf2f(q0.z); a0.w += v0 * bf2f(q0.w);
        }
    }
    ushort4 o;
    o.x = f2bf((a0.x + a1.x) + (a2.x + a3.x));
    o.y = f2bf((a0.y + a1.y) + (a2.y + a3.y));
    o.z = f2bf((a0.z + a1.z) + (a2.z + a3.z));
    o.w = f2bf((a0.w + a1.w) + (a2.w + a3.w));
    *(ushort4*)(cat + (size_t)wid * 2 * DIM + DIM + c4) = o;
}

// ---------------------------------------------------------------------------
// LDS-tiled GEMM: C = A[M_PAD,512] @ Bt[512,512]^T, 128x128 tile per block,
// 4 waves (2x2), each wave a 64x64 sub-tile (4x4 frags of 16x16x32 bf16 MFMA).
// LDS rows padded +8 bf16 (stride 144 B) -> conflict-free fragment reads.
// MODE 0: relu(acc+bias) -> bf16 hout.
// MODE 1: prelu(acc+bias) dot w2, column-reduced -> part[8][M_PAD] (fused GEMV).
// ---------------------------------------------------------------------------
#define LDSW 72   // 64 + 8 pad, elements

template <int MODE>
__global__ __launch_bounds__(256)
void k_gemm128(const unsigned short* __restrict__ A,
               const unsigned short* __restrict__ Bt,
               const float* __restrict__ bias,
               const float* __restrict__ pa,
               const float* __restrict__ w2,
               unsigned short* __restrict__ hout,
               float* __restrict__ part) {
    __shared__ unsigned short As[128 * LDSW];
    __shared__ unsigned short Bs[128 * LDSW];

    const int t    = threadIdx.x;
    const int lane = t & 63;
    const int w    = t >> 6;
    const int wr   = w >> 1, wc = w & 1;
    const int tn   = blockIdx.x & 3;          // 4 N-tiles
    const int tm   = blockIdx.x >> 2;         // 79 M-tiles
    const int gm0  = tm * 128, gn0 = tn * 128;

    // staging map: thread t loads 64 B of row (t>>1), col half (t&1)*32
    const int srow = t >> 1;
    const int scol = (t & 1) * 32;
    const unsigned short* gA = A  + (size_t)(gm0 + srow) * KDIM + scol;
    const unsigned short* gB = Bt + (size_t)(gn0 + srow) * KDIM + scol;
    unsigned short* wA = &As[srow * LDSW + scol];
    unsigned short* wB = &Bs[srow * LDSW + scol];

    const int r15 = lane & 15;
    const int kf  = (lane >> 4) * 8;

    f32x4 acc[4][4] = {};

    for (int ks = 0; ks < 8; ++ks) {
        f32x4 va0 = *(const f32x4*)(gA);
        f32x4 va1 = *(const f32x4*)(gA + 8);
        f32x4 va2 = *(const f32x4*)(gA + 16);
        f32x4 va3 = *(const f32x4*)(gA + 24);
        f32x4 vb0 = *(const f32x4*)(gB);
        f32x4 vb1 = *(const f32x4*)(gB + 8);
        f32x4 vb2 = *(const f32x4*)(gB + 16);
        f32x4 vb3 = *(const f32x4*)(gB + 24);
        __syncthreads();                     // prev iter's LDS reads done
        *(f32x4*)(wA)      = va0;
        *(f32x4*)(wA + 8)  = va1;
        *(f32x4*)(wA + 16) = va2;
        *(f32x4*)(wA + 24) = va3;
        *(f32x4*)(wB)      = vb0;
        *(f32x4*)(wB + 8)  = vb1;
        *(f32x4*)(wB + 16) = vb2;
        *(f32x4*)(wB + 24) = vb3;
        __syncthreads();                     // tile visible
        #pragma unroll
        for (int kk = 0; kk < 2; ++kk) {
            bf16x8 af[4], bf[4];
            #pragma unroll
            for (int m = 0; m < 4; ++m)
                af[m] = *(const bf16x8*)&As[(wr * 64 + m * 16 + r15) * LDSW + kk * 32 + kf];
            #pragma unroll
            for (int n = 0; n < 4; ++n)
                bf[n] = *(const bf16x8*)&Bs[(wc * 64 + n * 16 + r15) * LDSW + kk * 32 + kf];
            #pragma unroll
            for (int m = 0; m < 4; ++m)
                #pragma unroll
                for (int n = 0; n < 4; ++n)
                    acc[m][n] = __builtin_amdgcn_mfma_f32_16x16x32_bf16(af[m], bf[n], acc[m][n], 0, 0, 0);
        }
        gA += 64;
        gB += 64;
    }

    const int rq = lane >> 4;                // C row quad
    if (MODE == 0) {
        #pragma unroll
        for (int n = 0; n < 4; ++n) {
            int c = gn0 + wc * 64 + n * 16 + r15;
            float b = bias[c];
            #pragma unroll
            for (int m = 0; m < 4; ++m) {
                #pragma unroll
                for (int i = 0; i < 4; ++i) {
                    int row = gm0 + wr * 64 + m * 16 + rq * 4 + i;
                    float v = acc[m][n][i] + b;
                    v = v > 0.f ? v : 0.f;   // NaN from poison rows -> 0
                    hout[(size_t)row * HID + c] = f2bf(v);
                }
            }
        }
    } else {
        float rsum[4][4] = {};
        #pragma unroll
        for (int n = 0; n < 4; ++n) {
            int c = gn0 + wc * 64 + n * 16 + r15;
            float b = bias[c];
            float a = pa[c];
            float wv = w2[c];
            #pragma unroll
            for (int m = 0; m < 4; ++m)
                #pragma unroll
                for (int i = 0; i < 4; ++i) {
                    float v = acc[m][n][i] + b;
                    v = v > 0.f ? v : a * v;
                    rsum[m][i] += v * wv;
                }
        }
        // reduce over the 16 column-lanes; lane&15==0 holds the sum
        #pragma unroll
        for (int m = 0; m < 4; ++m)
            #pragma unroll
            for (int i = 0; i < 4; ++i) {
                float s = rsum[m][i];
                s += __shfl_xor(s, 1);
                s += __shfl_xor(s, 2);
                s += __shfl_xor(s, 4);
                s += __shfl_xor(s, 8);
                if (r15 == 0) {
                    int row = gm0 + wr * 64 + m * 16 + rq * 4 + i;
                    part[(size_t)(tn * 2 + wc) * M_PAD + row] = s;
                }
            }
    }
}

// ---------------------------------------------------------------------------
// pred[row] = sum_j part[j][row] + b2
// ---------------------------------------------------------------------------
__global__ void k_vout(const float* __restrict__ part, const float* __restrict__ b2,
                       float* __restrict__ pred) {
    int row = blockIdx.x * blockDim.x + threadIdx.x;
    if (row >= N_NODES) return;
    float s = b2[0];
    #pragma unroll
    for (int j = 0; j < 8; ++j) s += part[(size_t)j * M_PAD + row];
    pred[row] = s;
}

extern "C" void kernel_launch(void* const* d_in, const int* in_sizes, int n_in,
                              void* d_out, int out_size, void* d_ws, size_t ws_size,
                              hipStream_t stream) {
    const float* x    = (const float*)d_in[0];
    const int*   esrc = (const int*)  d_in[1];
    const int*   edst = (const int*)  d_in[2];
    const float* eval = (const float*)d_in[3];
    const float* Wc   = (const float*)d_in[4];
    const float* bc   = (const float*)d_in[5];
    const float* W1   = (const float*)d_in[6];
    const float* b1   = (const float*)d_in[7];
    const float* pa   = (const float*)d_in[8];
    const float* W2   = (const float*)d_in[9];
    const float* b2   = (const float*)d_in[10];
    float* pred = (float*)d_out;

    // workspace layout (16B-aligned), total ~24.8 MB
    char* w = (char*)d_ws;
    int*            deg   = (int*)w;                               //     40,960 B
    int*            offs  = (int*)(w + 40960);                     //     40,960 B
    int*            pos   = (int*)(w + 81920);                     //     40,960 B
    int2*           epack = (int2*)(w + 122880);                   //  2,560,000 B
    unsigned short* cat   = (unsigned short*)(w + 2682880);        // 10,354,688 B (M_PAD x 512)
    unsigned short* Wct   = (unsigned short*)(w + 13037568);       //    524,288 B
    unsigned short* W1t   = (unsigned short*)(w + 13561856);       //    524,288 B
    unsigned short* h     = (unsigned short*)(w + 14086144);       // 10,354,688 B (M_PAD x 512)
    float*          partb = (float*)(w + 24440832);                //    323,584 B (8 x M_PAD)

    // ---- fused prep (hist + cat_x + both weight transposes) ----
    hipMemsetAsync(deg, 0, 10240 * sizeof(int), stream);
    k_prep<<<5798, 256, 0, stream>>>(edst, deg, x, cat, Wc, Wct, W1, W1t);

    // ---- CSR scan + scatter ----
    k_scan   <<<1, 256, 0, stream>>>(deg, offs, pos);
    k_scatter<<<(N_EDGE + 255) / 256, 256, 0, stream>>>(esrc, edst, eval, pos, epack);

    // ---- gather-aggregate into cat second half ----
    k_agg<<<(N_NODES * 64 + 255) / 256, 256, 0, stream>>>(offs, epack, cat);

    // ---- tiled GEMMs: 79 M-tiles x 4 N-tiles = 316 blocks ----
    k_gemm128<0><<<316, 256, 0, stream>>>(cat, Wct, bc, nullptr, nullptr, h, nullptr);
    k_gemm128<1><<<316, 256, 0, stream>>>(h, W1t, b1, pa, W2, nullptr, partb);

    // ---- final partial reduce ----
    k_vout<<<(N_NODES + 255) / 256, 256, 0, stream>>>(partb, b2, pred);
}

// Round 7
// 132.962 us; speedup vs baseline: 9.3012x; 1.0162x over previous
//
#include <hip/hip_runtime.h>
#include <hip/hip_bf16.h>

#define N_NODES 10000
#define M_PAD   10112          // 79 * 128
#define DIM     256
#define HID     512
#define KDIM    512            // K for both GEMMs (2*DIM == HID == 512)
#define N_EDGE  320000

typedef __attribute__((ext_vector_type(4))) float  f32x4;
typedef __attribute__((ext_vector_type(8))) __bf16 bf16x8;

// round-to-nearest-even f32 -> bf16 bits
__device__ __forceinline__ unsigned short f2bf(float f) {
    union { float f; unsigned int u; } v; v.f = f;
    unsigned int r = v.u + 0x7FFFu + ((v.u >> 16) & 1u);
    return (unsigned short)(r >> 16);
}
// bf16 bits -> f32 (exact)
__device__ __forceinline__ float bf2f(unsigned short u) {
    union { unsigned int i; float f; } v; v.i = ((unsigned int)u) << 16;
    return v.f;
}

// ---------------------------------------------------------------------------
// zero deg[0..10240) -- replaces hipMemsetAsync (which captured as a ~42us
// fillBufferAligned in the graph)
// ---------------------------------------------------------------------------
__global__ void k_zero(int* __restrict__ deg) {
    int i = blockIdx.x * 256 + threadIdx.x;
    if (i < 10240) deg[i] = 0;
}

// ---------------------------------------------------------------------------
// Fused prep: blockIdx ranges dispatch 4 independent jobs
//   [0,1250)      : histogram of edge destinations
//   [1250,3750)   : cat[n][0..255] = bf16(x[n][*])
//   [3750,4774)   : Wct = bf16(Wc^T)
//   [4774,5798)   : W1t = bf16(W1^T)
// ---------------------------------------------------------------------------
__global__ void k_prep(const int* __restrict__ edst, int* __restrict__ deg,
                       const float* __restrict__ x, unsigned short* __restrict__ cat,
                       const float* __restrict__ Wc, unsigned short* __restrict__ Wct,
                       const float* __restrict__ W1, unsigned short* __restrict__ W1t) {
    int b = blockIdx.x;
    if (b < 1250) {
        int e = b * 256 + threadIdx.x;
        if (e < N_EDGE) atomicAdd(&deg[edst[e]], 1);
    } else if (b < 3750) {
        int t  = (b - 1250) * 256 + threadIdx.x;   // < 640000 exactly
        int n  = t >> 6;
        int c4 = (t & 63) * 4;
        f32x4 v = *(const f32x4*)(x + (size_t)n * DIM + c4);
        ushort4 o;
        o.x = f2bf(v.x); o.y = f2bf(v.y); o.z = f2bf(v.z); o.w = f2bf(v.w);
        *(ushort4*)(cat + (size_t)n * 2 * DIM + c4) = o;
    } else if (b < 4774) {
        int t = (b - 3750) * 256 + threadIdx.x;
        int k = t >> 9, n = t & 511;
        Wct[(size_t)n * 512 + k] = f2bf(Wc[(size_t)k * 512 + n]);
    } else {
        int t = (b - 4774) * 256 + threadIdx.x;
        int k = t >> 9, n = t & 511;
        W1t[(size_t)n * 512 + k] = f2bf(W1[(size_t)k * 512 + n]);
    }
}

// ---------------------------------------------------------------------------
// CSR build step 2: exclusive prefix scan (single block, 256 thr x 40 elems)
// ---------------------------------------------------------------------------
__global__ void k_scan(const int* __restrict__ deg, int* __restrict__ offs,
                       int* __restrict__ pos) {
    __shared__ int part[256];
    const int CH = 40;
    int t = threadIdx.x;
    int base = t * CH;
    int s = 0;
    for (int i = 0; i < CH; i++) {
        int idx = base + i;
        if (idx < N_NODES) s += deg[idx];
    }
    part[t] = s;
    __syncthreads();
    for (int off = 1; off < 256; off <<= 1) {
        int u = (t >= off) ? part[t - off] : 0;
        __syncthreads();
        part[t] += u;
        __syncthreads();
    }
    int run = part[t] - s;
    for (int i = 0; i < CH; i++) {
        int idx = base + i;
        if (idx < N_NODES) {
            offs[idx] = run;
            pos[idx]  = run;
            run += deg[idx];
        }
    }
    if (t == 255) offs[N_NODES] = run;
}

// ---------------------------------------------------------------------------
// CSR build step 3: scatter edges into dst-sorted (src, val_bits) pairs
// ---------------------------------------------------------------------------
__global__ void k_scatter(const int* __restrict__ esrc, const int* __restrict__ edst,
                          const float* __restrict__ eval, int* __restrict__ pos,
                          int2* __restrict__ epack) {
    int e = blockIdx.x * blockDim.x + threadIdx.x;
    if (e >= N_EDGE) return;
    int d = edst[e];
    int p = atomicAdd(&pos[d], 1);
    epack[p] = make_int2(esrc[e], __float_as_int(eval[e]));
}

// ---------------------------------------------------------------------------
// Aggregate: one wave per node. Lane l preloads edge record e0+l (one vector
// load covers the whole edge block), readlane-broadcasts it, and 4 row
// gathers fly concurrently into 4 independent accumulators.
// ---------------------------------------------------------------------------
__global__ void k_agg(const int* __restrict__ offs, const int2* __restrict__ epack,
                      unsigned short* __restrict__ cat) {
    int wid  = (blockIdx.x * blockDim.x + threadIdx.x) >> 6;
    int lane = threadIdx.x & 63;
    if (wid >= N_NODES) return;
    int e0 = offs[wid], e1 = offs[wid + 1];
    int c4 = lane * 4;
    f32x4 a0 = {0.f,0.f,0.f,0.f}, a1 = a0, a2 = a0, a3 = a0;
    for (int base = e0; base < e1; base += 64) {
        int m = e1 - base;
        if (m > 64) m = 64;
        int2 my = make_int2(0, 0);
        if (lane < m) my = epack[base + lane];
        int j = 0;
        for (; j + 4 <= m; j += 4) {
            int   s0 = __builtin_amdgcn_readlane(my.x, j);
            float v0 = __int_as_float(__builtin_amdgcn_readlane(my.y, j));
            int   s1 = __builtin_amdgcn_readlane(my.x, j + 1);
            float v1 = __int_as_float(__builtin_amdgcn_readlane(my.y, j + 1));
            int   s2 = __builtin_amdgcn_readlane(my.x, j + 2);
            float v2 = __int_as_float(__builtin_amdgcn_readlane(my.y, j + 2));
            int   s3 = __builtin_amdgcn_readlane(my.x, j + 3);
            float v3 = __int_as_float(__builtin_amdgcn_readlane(my.y, j + 3));
            ushort4 q0 = *(const ushort4*)(cat + (size_t)s0 * 2 * DIM + c4);
            ushort4 q1 = *(const ushort4*)(cat + (size_t)s1 * 2 * DIM + c4);
            ushort4 q2 = *(const ushort4*)(cat + (size_t)s2 * 2 * DIM + c4);
            ushort4 q3 = *(const ushort4*)(cat + (size_t)s3 * 2 * DIM + c4);
            a0.x += v0 * bf2f(q0.x); a0.y += v0 * bf2f(q0.y);
            a0.z += v0 * bf2f(q0.z); a0.w += v0 * bf2f(q0.w);
            a1.x += v1 * bf2f(q1.x); a1.y += v1 * bf2f(q1.y);
            a1.z += v1 * bf2f(q1.z); a1.w += v1 * bf2f(q1.w);
            a2.x += v2 * bf2f(q2.x); a2.y += v2 * bf2f(q2.y);
            a2.z += v2 * bf2f(q2.z); a2.w += v2 * bf2f(q2.w);
            a3.x += v3 * bf2f(q3.x); a3.y += v3 * bf2f(q3.y);
            a3.z += v3 * bf2f(q3.z); a3.w += v3 * bf2f(q3.w);
        }
        for (; j < m; ++j) {
            int   s0 = __builtin_amdgcn_readlane(my.x, j);
            float v0 = __int_as_float(__builtin_amdgcn_readlane(my.y, j));
            ushort4 q0 = *(const ushort4*)(cat + (size_t)s0 * 2 * DIM + c4);
            a0.x += v0 * bf2f(q0.x); a0.y += v0 * bf2f(q0.y);
            a0.z += v0 * bf2f(q0.z); a0.w += v0 * bf2f(q0.w);
        }
    }
    ushort4 o;
    o.x = f2bf((a0.x + a1.x) + (a2.x + a3.x));
    o.y = f2bf((a0.y + a1.y) + (a2.y + a3.y));
    o.z = f2bf((a0.z + a1.z) + (a2.z + a3.z));
    o.w = f2bf((a0.w + a1.w) + (a2.w + a3.w));
    *(ushort4*)(cat + (size_t)wid * 2 * DIM + DIM + c4) = o;
}

// ---------------------------------------------------------------------------
// LDS-tiled GEMM, 2-phase reg-prefetch pipeline:
//   prologue: load K-tile 0 -> regs
//   step ks : barrier; regs -> LDS; barrier; issue loads for ks+1; MFMA on ks
// 128x128 tile per block, 4 waves (2x2), 64x64 per wave, +8 pad (no conflicts).
// MODE 0: relu(acc+bias) -> bf16 hout.
// MODE 1: prelu(acc+bias) dot w2, column-reduced -> part[8][M_PAD] (fused GEMV).
// ---------------------------------------------------------------------------
#define LDSW 72   // 64 + 8 pad, elements

#define LOAD4(dst, p) { dst[0] = *(const f32x4*)(p); dst[1] = *(const f32x4*)((p) + 8); \
                        dst[2] = *(const f32x4*)((p) + 16); dst[3] = *(const f32x4*)((p) + 24); }
#define STORE4(p, src) { *(f32x4*)(p) = src[0]; *(f32x4*)((p) + 8) = src[1]; \
                         *(f32x4*)((p) + 16) = src[2]; *(f32x4*)((p) + 24) = src[3]; }

template <int MODE>
__global__ __launch_bounds__(256)
void k_gemm128(const unsigned short* __restrict__ A,
               const unsigned short* __restrict__ Bt,
               const float* __restrict__ bias,
               const float* __restrict__ pa,
               const float* __restrict__ w2,
               unsigned short* __restrict__ hout,
               float* __restrict__ part) {
    __shared__ unsigned short As[128 * LDSW];
    __shared__ unsigned short Bs[128 * LDSW];

    const int t    = threadIdx.x;
    const int lane = t & 63;
    const int w    = t >> 6;
    const int wr   = w >> 1, wc = w & 1;
    const int tn   = blockIdx.x & 3;          // 4 N-tiles
    const int tm   = blockIdx.x >> 2;         // 79 M-tiles
    const int gm0  = tm * 128, gn0 = tn * 128;

    // staging map: thread t loads 64 B of row (t>>1), col half (t&1)*32
    const int srow = t >> 1;
    const int scol = (t & 1) * 32;
    const unsigned short* gA = A  + (size_t)(gm0 + srow) * KDIM + scol;
    const unsigned short* gB = Bt + (size_t)(gn0 + srow) * KDIM + scol;
    unsigned short* wA = &As[srow * LDSW + scol];
    unsigned short* wB = &Bs[srow * LDSW + scol];

    const int r15 = lane & 15;
    const int kf  = (lane >> 4) * 8;

    f32x4 acc[4][4] = {};
    f32x4 va[4], vb[4];

    LOAD4(va, gA);                            // K-tile 0 in flight
    LOAD4(vb, gB);

    #pragma unroll
    for (int ks = 0; ks < 8; ++ks) {
        __syncthreads();                      // prev iter's LDS reads done
        STORE4(wA, va);
        STORE4(wB, vb);
        __syncthreads();                      // tile visible
        if (ks < 7) {                         // issue next tile's loads NOW;
            gA += 64; gB += 64;               // they fly under the 32 MFMAs
            LOAD4(va, gA);
            LOAD4(vb, gB);
        }
        #pragma unroll
        for (int kk = 0; kk < 2; ++kk) {
            bf16x8 af[4], bf[4];
            #pragma unroll
            for (int m = 0; m < 4; ++m)
                af[m] = *(const bf16x8*)&As[(wr * 64 + m * 16 + r15) * LDSW + kk * 32 + kf];
            #pragma unroll
            for (int n = 0; n < 4; ++n)
                bf[n] = *(const bf16x8*)&Bs[(wc * 64 + n * 16 + r15) * LDSW + kk * 32 + kf];
            #pragma unroll
            for (int m = 0; m < 4; ++m)
                #pragma unroll
                for (int n = 0; n < 4; ++n)
                    acc[m][n] = __builtin_amdgcn_mfma_f32_16x16x32_bf16(af[m], bf[n], acc[m][n], 0, 0, 0);
        }
    }

    const int rq = lane >> 4;                // C row quad
    if (MODE == 0) {
        #pragma unroll
        for (int n = 0; n < 4; ++n) {
            int c = gn0 + wc * 64 + n * 16 + r15;
            float b = bias[c];
            #pragma unroll
            for (int m = 0; m < 4; ++m) {
                #pragma unroll
                for (int i = 0; i < 4; ++i) {
                    int row = gm0 + wr * 64 + m * 16 + rq * 4 + i;
                    float v = acc[m][n][i] + b;
                    v = v > 0.f ? v : 0.f;   // NaN from poison rows -> 0
                    hout[(size_t)row * HID + c] = f2bf(v);
                }
            }
        }
    } else {
        float rsum[4][4] = {};
        #pragma unroll
        for (int n = 0; n < 4; ++n) {
            int c = gn0 + wc * 64 + n * 16 + r15;
            float b = bias[c];
            float a = pa[c];
            float wv = w2[c];
            #pragma unroll
            for (int m = 0; m < 4; ++m)
                #pragma unroll
                for (int i = 0; i < 4; ++i) {
                    float v = acc[m][n][i] + b;
                    v = v > 0.f ? v : a * v;
                    rsum[m][i] += v * wv;
                }
        }
        // reduce over the 16 column-lanes; lane&15==0 holds the sum
        #pragma unroll
        for (int m = 0; m < 4; ++m)
            #pragma unroll
            for (int i = 0; i < 4; ++i) {
                float s = rsum[m][i];
                s += __shfl_xor(s, 1);
                s += __shfl_xor(s, 2);
                s += __shfl_xor(s, 4);
                s += __shfl_xor(s, 8);
                if (r15 == 0) {
                    int row = gm0 + wr * 64 + m * 16 + rq * 4 + i;
                    part[(size_t)(tn * 2 + wc) * M_PAD + row] = s;
                }
            }
    }
}

// ---------------------------------------------------------------------------
// pred[row] = sum_j part[j][row] + b2
// ---------------------------------------------------------------------------
__global__ void k_vout(const float* __restrict__ part, const float* __restrict__ b2,
                       float* __restrict__ pred) {
    int row = blockIdx.x * blockDim.x + threadIdx.x;
    if (row >= N_NODES) return;
    float s = b2[0];
    #pragma unroll
    for (int j = 0; j < 8; ++j) s += part[(size_t)j * M_PAD + row];
    pred[row] = s;
}

extern "C" void kernel_launch(void* const* d_in, const int* in_sizes, int n_in,
                              void* d_out, int out_size, void* d_ws, size_t ws_size,
                              hipStream_t stream) {
    const float* x    = (const float*)d_in[0];
    const int*   esrc = (const int*)  d_in[1];
    const int*   edst = (const int*)  d_in[2];
    const float* eval = (const float*)d_in[3];
    const float* Wc   = (const float*)d_in[4];
    const float* bc   = (const float*)d_in[5];
    const float* W1   = (const float*)d_in[6];
    const float* b1   = (const float*)d_in[7];
    const float* pa   = (const float*)d_in[8];
    const float* W2   = (const float*)d_in[9];
    const float* b2   = (const float*)d_in[10];
    float* pred = (float*)d_out;

    // workspace layout (16B-aligned), total ~24.8 MB
    char* w = (char*)d_ws;
    int*            deg   = (int*)w;                               //     40,960 B
    int*            offs  = (int*)(w + 40960);                     //     40,960 B
    int*            pos   = (int*)(w + 81920);                     //     40,960 B
    int2*           epack = (int2*)(w + 122880);                   //  2,560,000 B
    unsigned short* cat   = (unsigned short*)(w + 2682880);        // 10,354,688 B (M_PAD x 512)
    unsigned short* Wct   = (unsigned short*)(w + 13037568);       //    524,288 B
    unsigned short* W1t   = (unsigned short*)(w + 13561856);       //    524,288 B
    unsigned short* h     = (unsigned short*)(w + 14086144);       // 10,354,688 B (M_PAD x 512)
    float*          partb = (float*)(w + 24440832);                //    323,584 B (8 x M_PAD)

    // ---- zero deg (own kernel; graph-captured memset was ~42us) ----
    k_zero<<<40, 256, 0, stream>>>(deg);

    // ---- fused prep (hist + cat_x + both weight transposes) ----
    k_prep<<<5798, 256, 0, stream>>>(edst, deg, x, cat, Wc, Wct, W1, W1t);

    // ---- CSR scan + scatter ----
    k_scan   <<<1, 256, 0, stream>>>(deg, offs, pos);
    k_scatter<<<(N_EDGE + 255) / 256, 256, 0, stream>>>(esrc, edst, eval, pos, epack);

    // ---- gather-aggregate into cat second half ----
    k_agg<<<(N_NODES * 64 + 255) / 256, 256, 0, stream>>>(offs, epack, cat);

    // ---- tiled GEMMs: 79 M-tiles x 4 N-tiles = 316 blocks ----
    k_gemm128<0><<<316, 256, 0, stream>>>(cat, Wct, bc, nullptr, nullptr, h, nullptr);
    k_gemm128<1><<<316, 256, 0, stream>>>(h, W1t, b1, pa, W2, nullptr, partb);

    // ---- final partial reduce ----
    k_vout<<<(N_NODES + 255) / 256, 256, 0, stream>>>(partb, b2, pred);
}

// Round 8
// 85.494 us; speedup vs baseline: 14.4654x; 1.5552x over previous
//
#include <hip/hip_runtime.h>
#include <hip/hip_bf16.h>

#define N_NODES 10000
#define M_PAD   10112          // 79 * 128
#define DIM     256
#define HID     512
#define KDIM    512            // K for both GEMMs (2*DIM == HID == 512)
#define N_EDGE  320000
#define ELL_W   128            // max degree capacity (mean 32, sigma 5.7)

typedef __attribute__((ext_vector_type(4))) float  f32x4;
typedef __attribute__((ext_vector_type(8))) __bf16 bf16x8;

// round-to-nearest-even f32 -> bf16 bits
__device__ __forceinline__ unsigned short f2bf(float f) {
    union { float f; unsigned int u; } v; v.f = f;
    unsigned int r = v.u + 0x7FFFu + ((v.u >> 16) & 1u);
    return (unsigned short)(r >> 16);
}
// bf16 bits -> f32 (exact)
__device__ __forceinline__ float bf2f(unsigned short u) {
    union { unsigned int i; float f; } v; v.i = ((unsigned int)u) << 16;
    return v.f;
}

// ---------------------------------------------------------------------------
// zero deg[0..10240)
// ---------------------------------------------------------------------------
__global__ void k_zero(int* __restrict__ deg) {
    int i = blockIdx.x * 256 + threadIdx.x;
    if (i < 10240) deg[i] = 0;
}

// ---------------------------------------------------------------------------
// Fused prep: blockIdx ranges dispatch 4 independent jobs
//   [0,1250)      : ELL scatter  ell[d][slot] = (src, val)   (slot via atomic)
//   [1250,3750)   : cat[n][0..255] = bf16(x[n][*])
//   [3750,4774)   : Wct = bf16(Wc^T)
//   [4774,5798)   : W1t = bf16(W1^T)
// ---------------------------------------------------------------------------
__global__ void k_prep(const int* __restrict__ esrc, const int* __restrict__ edst,
                       const float* __restrict__ eval,
                       int* __restrict__ deg, int2* __restrict__ ell,
                       const float* __restrict__ x, unsigned short* __restrict__ cat,
                       const float* __restrict__ Wc, unsigned short* __restrict__ Wct,
                       const float* __restrict__ W1, unsigned short* __restrict__ W1t) {
    int b = blockIdx.x;
    if (b < 1250) {
        int e = b * 256 + threadIdx.x;
        if (e < N_EDGE) {
            int d = edst[e];
            int slot = atomicAdd(&deg[d], 1);
            if (slot < ELL_W)   // safety clamp; never triggers for this input
                ell[(size_t)d * ELL_W + slot] = make_int2(esrc[e], __float_as_int(eval[e]));
        }
    } else if (b < 3750) {
        int t  = (b - 1250) * 256 + threadIdx.x;   // < 640000 exactly
        int n  = t >> 6;
        int c4 = (t & 63) * 4;
        f32x4 v = *(const f32x4*)(x + (size_t)n * DIM + c4);
        ushort4 o;
        o.x = f2bf(v.x); o.y = f2bf(v.y); o.z = f2bf(v.z); o.w = f2bf(v.w);
        *(ushort4*)(cat + (size_t)n * 2 * DIM + c4) = o;
    } else if (b < 4774) {
        int t = (b - 3750) * 256 + threadIdx.x;
        int k = t >> 9, n = t & 511;
        Wct[(size_t)n * 512 + k] = f2bf(Wc[(size_t)k * 512 + n]);
    } else {
        int t = (b - 4774) * 256 + threadIdx.x;
        int k = t >> 9, n = t & 511;
        W1t[(size_t)n * 512 + k] = f2bf(W1[(size_t)k * 512 + n]);
    }
}

// ---------------------------------------------------------------------------
// Aggregate: one wave per node. Lane l preloads ELL record l (coalesced 8B),
// readlane-broadcasts it; 4 row gathers in flight into 4 accumulators.
// ---------------------------------------------------------------------------
__global__ void k_agg(const int* __restrict__ deg, const int2* __restrict__ ell,
                      unsigned short* __restrict__ cat) {
    int wid  = (blockIdx.x * blockDim.x + threadIdx.x) >> 6;
    int lane = threadIdx.x & 63;
    if (wid >= N_NODES) return;
    int cnt = deg[wid];
    if (cnt > ELL_W) cnt = ELL_W;
    const int2* row = ell + (size_t)wid * ELL_W;
    int c4 = lane * 4;
    f32x4 a0 = {0.f,0.f,0.f,0.f}, a1 = a0, a2 = a0, a3 = a0;
    for (int base = 0; base < cnt; base += 64) {
        int m = cnt - base;
        if (m > 64) m = 64;
        int2 my = make_int2(0, 0);
        if (lane < m) my = row[base + lane];
        int j = 0;
        for (; j + 4 <= m; j += 4) {
            int   s0 = __builtin_amdgcn_readlane(my.x, j);
            float v0 = __int_as_float(__builtin_amdgcn_readlane(my.y, j));
            int   s1 = __builtin_amdgcn_readlane(my.x, j + 1);
            float v1 = __int_as_float(__builtin_amdgcn_readlane(my.y, j + 1));
            int   s2 = __builtin_amdgcn_readlane(my.x, j + 2);
            float v2 = __int_as_float(__builtin_amdgcn_readlane(my.y, j + 2));
            int   s3 = __builtin_amdgcn_readlane(my.x, j + 3);
            float v3 = __int_as_float(__builtin_amdgcn_readlane(my.y, j + 3));
            ushort4 q0 = *(const ushort4*)(cat + (size_t)s0 * 2 * DIM + c4);
            ushort4 q1 = *(const ushort4*)(cat + (size_t)s1 * 2 * DIM + c4);
            ushort4 q2 = *(const ushort4*)(cat + (size_t)s2 * 2 * DIM + c4);
            ushort4 q3 = *(const ushort4*)(cat + (size_t)s3 * 2 * DIM + c4);
            a0.x += v0 * bf2f(q0.x); a0.y += v0 * bf2f(q0.y);
            a0.z += v0 * bf2f(q0.z); a0.w += v0 * bf2f(q0.w);
            a1.x += v1 * bf2f(q1.x); a1.y += v1 * bf2f(q1.y);
            a1.z += v1 * bf2f(q1.z); a1.w += v1 * bf2f(q1.w);
            a2.x += v2 * bf2f(q2.x); a2.y += v2 * bf2f(q2.y);
            a2.z += v2 * bf2f(q2.z); a2.w += v2 * bf2f(q2.w);
            a3.x += v3 * bf2f(q3.x); a3.y += v3 * bf2f(q3.y);
            a3.z += v3 * bf2f(q3.z); a3.w += v3 * bf2f(q3.w);
        }
        for (; j < m; ++j) {
            int   s0 = __builtin_amdgcn_readlane(my.x, j);
            float v0 = __int_as_float(__builtin_amdgcn_readlane(my.y, j));
            ushort4 q0 = *(const ushort4*)(cat + (size_t)s0 * 2 * DIM + c4);
            a0.x += v0 * bf2f(q0.x); a0.y += v0 * bf2f(q0.y);
            a0.z += v0 * bf2f(q0.z); a0.w += v0 * bf2f(q0.w);
        }
    }
    ushort4 o;
    o.x = f2bf((a0.x + a1.x) + (a2.x + a3.x));
    o.y = f2bf((a0.y + a1.y) + (a2.y + a3.y));
    o.z = f2bf((a0.z + a1.z) + (a2.z + a3.z));
    o.w = f2bf((a0.w + a1.w) + (a2.w + a3.w));
    *(ushort4*)(cat + (size_t)wid * 2 * DIM + DIM + c4) = o;
}

// ---------------------------------------------------------------------------
// LDS-tiled GEMM, double-buffered: ONE barrier per K-step.
//   step ks: issue loads for ks+1 -> regs; MFMA on buf[cur]; regs -> buf[cur^1];
//            barrier.
// 128x128 tile per block, 4 waves (2x2), 64x64 per wave, +8 pad (no conflicts).
// MODE 0: relu(acc+bias) -> bf16 hout.
// MODE 1: prelu(acc+bias) dot w2, column-reduced -> part[8][M_PAD] (fused GEMV).
// ---------------------------------------------------------------------------
#define LDSW 72   // 64 + 8 pad, elements

#define LOAD4(dst, p) { dst[0] = *(const f32x4*)(p); dst[1] = *(const f32x4*)((p) + 8); \
                        dst[2] = *(const f32x4*)((p) + 16); dst[3] = *(const f32x4*)((p) + 24); }
#define STORE4(p, src) { *(f32x4*)(p) = src[0]; *(f32x4*)((p) + 8) = src[1]; \
                         *(f32x4*)((p) + 16) = src[2]; *(f32x4*)((p) + 24) = src[3]; }

template <int MODE>
__global__ __launch_bounds__(256)
void k_gemm128(const unsigned short* __restrict__ A,
               const unsigned short* __restrict__ Bt,
               const float* __restrict__ bias,
               const float* __restrict__ pa,
               const float* __restrict__ w2,
               unsigned short* __restrict__ hout,
               float* __restrict__ part) {
    __shared__ unsigned short As[2][128 * LDSW];
    __shared__ unsigned short Bs[2][128 * LDSW];

    const int t    = threadIdx.x;
    const int lane = t & 63;
    const int w    = t >> 6;
    const int wr   = w >> 1, wc = w & 1;
    const int tn   = blockIdx.x & 3;          // 4 N-tiles
    const int tm   = blockIdx.x >> 2;         // 79 M-tiles
    const int gm0  = tm * 128, gn0 = tn * 128;

    // staging map: thread t loads 64 B of row (t>>1), col half (t&1)*32
    const int srow = t >> 1;
    const int scol = (t & 1) * 32;
    const unsigned short* gA = A  + (size_t)(gm0 + srow) * KDIM + scol;
    const unsigned short* gB = Bt + (size_t)(gn0 + srow) * KDIM + scol;
    const int woff = srow * LDSW + scol;

    const int r15 = lane & 15;
    const int kf  = (lane >> 4) * 8;

    f32x4 acc[4][4] = {};
    f32x4 va[4], vb[4];

    LOAD4(va, gA);                            // K-tile 0
    LOAD4(vb, gB);
    STORE4(&As[0][woff], va);
    STORE4(&Bs[0][woff], vb);
    __syncthreads();                          // buf0 ready

    #pragma unroll
    for (int ks = 0; ks < 8; ++ks) {
        const int cur = ks & 1;
        if (ks < 7) {                         // issue next tile's loads NOW;
            gA += 64; gB += 64;               // covered by the MFMA phase below
            LOAD4(va, gA);
            LOAD4(vb, gB);
        }
        #pragma unroll
        for (int kk = 0; kk < 2; ++kk) {
            bf16x8 af[4], bf[4];
            #pragma unroll
            for (int m = 0; m < 4; ++m)
                af[m] = *(const bf16x8*)&As[cur][(wr * 64 + m * 16 + r15) * LDSW + kk * 32 + kf];
            #pragma unroll
            for (int n = 0; n < 4; ++n)
                bf[n] = *(const bf16x8*)&Bs[cur][(wc * 64 + n * 16 + r15) * LDSW + kk * 32 + kf];
            #pragma unroll
            for (int m = 0; m < 4; ++m)
                #pragma unroll
                for (int n = 0; n < 4; ++n)
                    acc[m][n] = __builtin_amdgcn_mfma_f32_16x16x32_bf16(af[m], bf[n], acc[m][n], 0, 0, 0);
        }
        if (ks < 7) {                         // write next tile to the OTHER buf
            STORE4(&As[cur ^ 1][woff], va);
            STORE4(&Bs[cur ^ 1][woff], vb);
            __syncthreads();                  // next buf ready (prev reads done)
        }
    }

    const int rq = lane >> 4;                // C row quad
    if (MODE == 0) {
        #pragma unroll
        for (int n = 0; n < 4; ++n) {
            int c = gn0 + wc * 64 + n * 16 + r15;
            float b = bias[c];
            #pragma unroll
            for (int m = 0; m < 4; ++m) {
                #pragma unroll
                for (int i = 0; i < 4; ++i) {
                    int row = gm0 + wr * 64 + m * 16 + rq * 4 + i;
                    float v = acc[m][n][i] + b;
                    v = v > 0.f ? v : 0.f;   // NaN/garbage from pad rows -> 0
                    hout[(size_t)row * HID + c] = f2bf(v);
                }
            }
        }
    } else {
        float rsum[4][4] = {};
        #pragma unroll
        for (int n = 0; n < 4; ++n) {
            int c = gn0 + wc * 64 + n * 16 + r15;
            float b = bias[c];
            float a = pa[c];
            float wv = w2[c];
            #pragma unroll
            for (int m = 0; m < 4; ++m)
                #pragma unroll
                for (int i = 0; i < 4; ++i) {
                    float v = acc[m][n][i] + b;
                    v = v > 0.f ? v : a * v;
                    rsum[m][i] += v * wv;
                }
        }
        // reduce over the 16 column-lanes; lane&15==0 holds the sum
        #pragma unroll
        for (int m = 0; m < 4; ++m)
            #pragma unroll
            for (int i = 0; i < 4; ++i) {
                float s = rsum[m][i];
                s += __shfl_xor(s, 1);
                s += __shfl_xor(s, 2);
                s += __shfl_xor(s, 4);
                s += __shfl_xor(s, 8);
                if (r15 == 0) {
                    int row = gm0 + wr * 64 + m * 16 + rq * 4 + i;
                    part[(size_t)(tn * 2 + wc) * M_PAD + row] = s;
                }
            }
    }
}

// ---------------------------------------------------------------------------
// pred[row] = sum_j part[j][row] + b2
// ---------------------------------------------------------------------------
__global__ void k_vout(const float* __restrict__ part, const float* __restrict__ b2,
                       float* __restrict__ pred) {
    int row = blockIdx.x * blockDim.x + threadIdx.x;
    if (row >= N_NODES) return;
    float s = b2[0];
    #pragma unroll
    for (int j = 0; j < 8; ++j) s += part[(size_t)j * M_PAD + row];
    pred[row] = s;
}

extern "C" void kernel_launch(void* const* d_in, const int* in_sizes, int n_in,
                              void* d_out, int out_size, void* d_ws, size_t ws_size,
                              hipStream_t stream) {
    const float* x    = (const float*)d_in[0];
    const int*   esrc = (const int*)  d_in[1];
    const int*   edst = (const int*)  d_in[2];
    const float* eval = (const float*)d_in[3];
    const float* Wc   = (const float*)d_in[4];
    const float* bc   = (const float*)d_in[5];
    const float* W1   = (const float*)d_in[6];
    const float* b1   = (const float*)d_in[7];
    const float* pa   = (const float*)d_in[8];
    const float* W2   = (const float*)d_in[9];
    const float* b2   = (const float*)d_in[10];
    float* pred = (float*)d_out;

    // workspace layout (16B-aligned), total ~32.6 MB
    char* w = (char*)d_ws;
    int*            deg   = (int*)w;                               //     40,960 B
    int2*           ell   = (int2*)(w + 40960);                    // 10,485,760 B (10240 x 128 x 8)
    unsigned short* cat   = (unsigned short*)(w + 10526720);       // 10,354,688 B (M_PAD x 512)
    unsigned short* Wct   = (unsigned short*)(w + 20881408);       //    524,288 B
    unsigned short* W1t   = (unsigned short*)(w + 21405696);       //    524,288 B
    unsigned short* h     = (unsigned short*)(w + 21929984);       // 10,354,688 B (M_PAD x 512)
    float*          partb = (float*)(w + 32284672);                //    323,584 B (8 x M_PAD)

    // ---- zero slot counters ----
    k_zero<<<40, 256, 0, stream>>>(deg);

    // ---- fused prep (ELL scatter + cat_x + both weight transposes) ----
    k_prep<<<5798, 256, 0, stream>>>(esrc, edst, eval, deg, ell, x, cat, Wc, Wct, W1, W1t);

    // ---- gather-aggregate into cat second half ----
    k_agg<<<(N_NODES * 64 + 255) / 256, 256, 0, stream>>>(deg, ell, cat);

    // ---- tiled GEMMs: 79 M-tiles x 4 N-tiles = 316 blocks ----
    k_gemm128<0><<<316, 256, 0, stream>>>(cat, Wct, bc, nullptr, nullptr, h, nullptr);
    k_gemm128<1><<<316, 256, 0, stream>>>(h, W1t, b1, pa, W2, nullptr, partb);

    // ---- final partial reduce ----
    k_vout<<<(N_NODES + 255) / 256, 256, 0, stream>>>(partb, b2, pred);
}